// Round 1
// baseline (340.160 us; speedup 1.0000x reference)
//
#include <hip/hip_runtime.h>
#include <hip/hip_bf16.h>

#define TT 8
#define CC 128
#define DD 64
#define HWp 9216
#define PP 16
#define XB_STRIDE 152   // bf16 elems per pixel row (128 + 24 pad) = 304B, 16B-aligned
#define QKV_STRIDE 264  // bf16 elems per (t,p) row (256 + 8 pad) = 528B, 16B-aligned

typedef __attribute__((ext_vector_type(8))) short short8;
typedef __attribute__((ext_vector_type(4))) short short4v;
typedef __attribute__((ext_vector_type(4))) float floatx4;

__device__ __forceinline__ short f2bf(float f) {
    __hip_bfloat16 h = __float2bfloat16(f);
    return __builtin_bit_cast(short, h);
}
__device__ __forceinline__ float bf2f(short s) {
    unsigned u = ((unsigned)(unsigned short)s) << 16;
    return __builtin_bit_cast(float, u);
}

__global__ __launch_bounds__(256, 2) void ta_kernel(
    const float* __restrict__ x,
    const float* __restrict__ Wq, const float* __restrict__ bq,
    const float* __restrict__ Wk, const float* __restrict__ bk,
    const float* __restrict__ Wv, const float* __restrict__ bv,
    float* __restrict__ out)
{
    __shared__ short xb[PP * XB_STRIDE];              // 4864 B
    __shared__ short qkv[TT * PP * QKV_STRIDE];       // 67584 B

    const int tid  = threadIdx.x;
    const int wave = tid >> 6;
    const int lane = tid & 63;
    const int quad = lane >> 4;
    const int l16  = lane & 15;

    const int blk = blockIdx.x;
    const int b   = blk / (HWp / PP);
    const int p0  = (blk % (HWp / PP)) * PP;

    // ---- Preload weight A-fragments + biases into registers ----
    // Stacked f rows: [0,64) = Wq, [64,128) = Wk, [128,256) = Wv.
    // Wave w owns f-tiles 4w..4w+3 (f0 = (4w+i)*16).
    // A-frag layout (16x16x32): A[m = lane&15][k = quad*8 + j], k = channel c.
    short8 wfrag[4][4];   // [tile][kchunk]
    float  bias[4][4];    // [tile][reg]
#pragma unroll
    for (int i = 0; i < 4; ++i) {
        const int f0  = (wave * 4 + i) * 16;
        const int row = f0 + l16;
        const float* wrow;
        if (row < DD)            wrow = Wq + row * CC;
        else if (row < 2 * DD)   wrow = Wk + (row - DD) * CC;
        else                     wrow = Wv + (row - 2 * DD) * CC;
#pragma unroll
        for (int kc = 0; kc < 4; ++kc) {
            const float* src = wrow + kc * 32 + quad * 8;
            short8 v;
#pragma unroll
            for (int j = 0; j < 8; ++j) v[j] = f2bf(src[j]);
            wfrag[i][kc] = v;
        }
        const int fb = f0 + quad * 4;   // rows this lane accumulates (D layout)
        const float* bsrc; int off;
        if (fb < DD)            { bsrc = bq; off = fb; }
        else if (fb < 2 * DD)   { bsrc = bk; off = fb - DD; }
        else                    { bsrc = bv; off = fb - 2 * DD; }
#pragma unroll
        for (int r = 0; r < 4; ++r) bias[i][r] = bsrc[off + r];
    }

    // ---- Projection: per t, stage x tile to LDS (bf16), MFMA -> qkv LDS ----
    for (int t = 0; t < TT; ++t) {
        __syncthreads();   // xb from previous iteration fully consumed
        {
            // 128c x 16p floats; thread -> (c = tid>>2 (+64), p4 = (tid&3)*4), float4 along p
            const int c0 = tid >> 2;
            const int p4 = (tid & 3) * 4;
            const float* xs = x + ((size_t)((b * TT + t) * CC)) * HWp + p0 + p4;
#pragma unroll
            for (int pass = 0; pass < 2; ++pass) {
                const int c = c0 + pass * 64;
                float4 v = *(const float4*)(xs + (size_t)c * HWp);
                xb[(p4 + 0) * XB_STRIDE + c] = f2bf(v.x);
                xb[(p4 + 1) * XB_STRIDE + c] = f2bf(v.y);
                xb[(p4 + 2) * XB_STRIDE + c] = f2bf(v.z);
                xb[(p4 + 3) * XB_STRIDE + c] = f2bf(v.w);
            }
        }
        __syncthreads();

        // D = A(W: f x c) * B(x: c x p).  B-frag: B[k = quad*8+j][n = lane&15],
        // read as contiguous 8 bf16 from xb[p][c] rows (ds_read_b128).
        floatx4 acc[4];
#pragma unroll
        for (int i = 0; i < 4; ++i)
#pragma unroll
            for (int r = 0; r < 4; ++r) acc[i][r] = 0.f;
#pragma unroll
        for (int kc = 0; kc < 4; ++kc) {
            short8 xf = *(const short8*)&xb[l16 * XB_STRIDE + kc * 32 + quad * 8];
#pragma unroll
            for (int i = 0; i < 4; ++i)
                acc[i] = __builtin_amdgcn_mfma_f32_16x16x32_bf16(wfrag[i][kc], xf, acc[i], 0, 0, 0);
        }
        // D layout: col(n=p) = lane&15, row(m=f) = quad*4 + r.
        // Store qkv[t][p][f] bf16, 4 consecutive f per lane -> ds_write_b64.
#pragma unroll
        for (int i = 0; i < 4; ++i) {
            const int f0 = (wave * 4 + i) * 16 + quad * 4;
            short4v o;
#pragma unroll
            for (int r = 0; r < 4; ++r) o[r] = f2bf(acc[i][r] + bias[i][r]);
            *(short4v*)&qkv[(t * PP + l16) * QKV_STRIDE + f0] = o;
        }
    }
    __syncthreads();

    // ---- Attention: 16 threads per pixel = (tq 8) x (e-half 2), fp32 VALU ----
    {
        const int p  = tid & 15;
        const int g  = tid >> 4;
        const int tq = g >> 1;
        const int e0 = (g & 1) * 64;

        const short* qrow = &qkv[(tq * PP + p) * QKV_STRIDE];
        float qv[DD];
#pragma unroll
        for (int dc = 0; dc < 8; ++dc) {
            short8 v = *(const short8*)(qrow + dc * 8);
#pragma unroll
            for (int j = 0; j < 8; ++j) qv[dc * 8 + j] = bf2f(v[j]);
        }
        float sc[TT];
#pragma unroll
        for (int s = 0; s < TT; ++s) {
            const short* krow = &qkv[(s * PP + p) * QKV_STRIDE + DD];
            float a = 0.f;
#pragma unroll
            for (int dc = 0; dc < 8; ++dc) {
                short8 v = *(const short8*)(krow + dc * 8);
#pragma unroll
                for (int j = 0; j < 8; ++j) a += qv[dc * 8 + j] * bf2f(v[j]);
            }
            sc[s] = a * 0.125f;   // 1/sqrt(64)
        }
        float m = sc[0];
#pragma unroll
        for (int s = 1; s < TT; ++s) m = fmaxf(m, sc[s]);
        float sum = 0.f;
#pragma unroll
        for (int s = 0; s < TT; ++s) { sc[s] = __expf(sc[s] - m); sum += sc[s]; }
        const float inv = 1.f / sum;
#pragma unroll
        for (int s = 0; s < TT; ++s) sc[s] *= inv;

        float o[64];
#pragma unroll
        for (int j = 0; j < 64; ++j) o[j] = 0.f;
#pragma unroll
        for (int s = 0; s < TT; ++s) {
            const short* vrow = &qkv[(s * PP + p) * QKV_STRIDE + 2 * DD + e0];
            const float a = sc[s];
#pragma unroll
            for (int ec = 0; ec < 8; ++ec) {
                short8 v = *(const short8*)(vrow + ec * 8);
#pragma unroll
                for (int j = 0; j < 8; ++j) o[ec * 8 + j] += a * bf2f(v[j]);
            }
        }
        // out[b][tq][e][h][w]; lanes 0..15 = consecutive pixels -> 64B segments
        float* op = out + ((size_t)((b * TT + tq) * CC + e0)) * HWp + p0 + p;
#pragma unroll
        for (int e = 0; e < 64; ++e) op[(size_t)e * HWp] = o[e];
    }
}

extern "C" void kernel_launch(void* const* d_in, const int* in_sizes, int n_in,
                              void* d_out, int out_size, void* d_ws, size_t ws_size,
                              hipStream_t stream) {
    const float* x  = (const float*)d_in[0];
    const float* Wq = (const float*)d_in[1];
    const float* bq = (const float*)d_in[2];
    const float* Wk = (const float*)d_in[3];
    const float* bk = (const float*)d_in[4];
    const float* Wv = (const float*)d_in[5];
    const float* bv = (const float*)d_in[6];
    float* out = (float*)d_out;

    const int blocks = 4 * (HWp / PP);   // B=4, 576 pixel-tiles per batch
    ta_kernel<<<blocks, 256, 0, stream>>>(x, Wq, bq, Wk, bk, Wv, bv, out);
}

// Round 2
// 324.702 us; speedup vs baseline: 1.0476x; 1.0476x over previous
//
#include <hip/hip_runtime.h>
#include <hip/hip_bf16.h>

#define TT 8
#define CC 128
#define DD 64
#define HWp 9216
#define PP 16
#define XB_STRIDE 152   // bf16 elems per pixel row (128 + 24 pad) = 304B, 16B-aligned
#define QKV_STRIDE 264  // bf16 elems per (t,p) row (256 + 8 pad) = 528B, 16B-aligned

typedef __attribute__((ext_vector_type(8))) short short8;
typedef __attribute__((ext_vector_type(4))) short short4v;
typedef __attribute__((ext_vector_type(4))) float floatx4;

__device__ __forceinline__ short f2bf(float f) {
    __hip_bfloat16 h = __float2bfloat16(f);
    return __builtin_bit_cast(short, h);
}
__device__ __forceinline__ float bf2f(short s) {
    unsigned u = ((unsigned)(unsigned short)s) << 16;
    return __builtin_bit_cast(float, u);
}

// block = 512 threads = 8 waves; 2 blocks/CU (LDS-limited) = 16 waves/CU.
__global__ __launch_bounds__(512, 4) void ta_kernel(
    const float* __restrict__ x,
    const float* __restrict__ Wq, const float* __restrict__ bq,
    const float* __restrict__ Wk, const float* __restrict__ bk,
    const float* __restrict__ Wv, const float* __restrict__ bv,
    float* __restrict__ out)
{
    __shared__ short xb[PP * XB_STRIDE];              // 4864 B
    __shared__ short qkv[TT * PP * QKV_STRIDE];       // 67584 B

    const int tid  = threadIdx.x;
    const int wave = tid >> 6;      // 0..7
    const int lane = tid & 63;
    const int quad = lane >> 4;
    const int l16  = lane & 15;

    const int blk = blockIdx.x;
    const int b   = blk / (HWp / PP);
    const int p0  = (blk % (HWp / PP)) * PP;

    // ---- Preload weight A-fragments + biases into registers ----
    // Stacked f rows: [0,64) = Wq, [64,128) = Wk, [128,256) = Wv.
    // Wave w owns f-tiles 2w, 2w+1 (f0 = (2w+i)*16).
    // A-frag (16x16x32): A[m = lane&15][k = quad*8 + j], k = channel c.
    short8 wfrag[2][4];   // [tile][kchunk]
    float  bias[2][4];    // [tile][reg]
#pragma unroll
    for (int i = 0; i < 2; ++i) {
        const int f0  = (wave * 2 + i) * 16;
        const int row = f0 + l16;
        const float* wrow;
        if (row < DD)            wrow = Wq + row * CC;
        else if (row < 2 * DD)   wrow = Wk + (row - DD) * CC;
        else                     wrow = Wv + (row - 2 * DD) * CC;
#pragma unroll
        for (int kc = 0; kc < 4; ++kc) {
            const float* src = wrow + kc * 32 + quad * 8;
            short8 v;
#pragma unroll
            for (int j = 0; j < 8; ++j) v[j] = f2bf(src[j]);
            wfrag[i][kc] = v;
        }
        const int fb = f0 + quad * 4;   // rows this lane accumulates (D layout)
        const float* bsrc; int off;
        if (fb < DD)            { bsrc = bq; off = fb; }
        else if (fb < 2 * DD)   { bsrc = bk; off = fb - DD; }
        else                    { bsrc = bv; off = fb - 2 * DD; }
#pragma unroll
        for (int r = 0; r < 4; ++r) bias[i][r] = bsrc[off + r];
    }

    // ---- Projection: per t, stage x tile (bf16) -> LDS, MFMA -> qkv LDS ----
    // 512 threads cover 128c x 16p in one float4 each; prefetch t+1 into regs.
    const int c0 = tid >> 2;            // 0..127
    const int p4 = (tid & 3) * 4;       // 0,4,8,12
    const float* xsrc0 = x + ((size_t)(b * TT) * CC + c0) * HWp + p0 + p4;

    float4 cur = *(const float4*)xsrc0;
    for (int t = 0; t < TT; ++t) {
        float4 nxt = cur;
        if (t < TT - 1)
            nxt = *(const float4*)(xsrc0 + (size_t)(t + 1) * CC * HWp);  // in flight across this iter

        __syncthreads();   // xb from previous iteration fully consumed
        xb[(p4 + 0) * XB_STRIDE + c0] = f2bf(cur.x);
        xb[(p4 + 1) * XB_STRIDE + c0] = f2bf(cur.y);
        xb[(p4 + 2) * XB_STRIDE + c0] = f2bf(cur.z);
        xb[(p4 + 3) * XB_STRIDE + c0] = f2bf(cur.w);
        __syncthreads();

        // D = A(W: f x c) * B(x: c x p). B-frag: B[k = quad*8+j][n = lane&15],
        // contiguous 8 bf16 from xb[p][c] rows (ds_read_b128).
        floatx4 acc[2];
#pragma unroll
        for (int i = 0; i < 2; ++i)
#pragma unroll
            for (int r = 0; r < 4; ++r) acc[i][r] = 0.f;
#pragma unroll
        for (int kc = 0; kc < 4; ++kc) {
            short8 xf = *(const short8*)&xb[l16 * XB_STRIDE + kc * 32 + quad * 8];
            acc[0] = __builtin_amdgcn_mfma_f32_16x16x32_bf16(wfrag[0][kc], xf, acc[0], 0, 0, 0);
            acc[1] = __builtin_amdgcn_mfma_f32_16x16x32_bf16(wfrag[1][kc], xf, acc[1], 0, 0, 0);
        }
        // D layout: col(n=p) = lane&15, row(m=f) = quad*4 + r.
#pragma unroll
        for (int i = 0; i < 2; ++i) {
            const int f0 = (wave * 2 + i) * 16 + quad * 4;
            short4v o;
#pragma unroll
            for (int r = 0; r < 4; ++r) o[r] = f2bf(acc[i][r] + bias[i][r]);
            *(short4v*)&qkv[(t * PP + l16) * QKV_STRIDE + f0] = o;
        }
        cur = nxt;
    }
    __syncthreads();

    // ---- Attention: 32 threads/pixel = (tq 8) x (e-quarter 4), fp32 VALU ----
    {
        const int p  = tid & 15;
        const int g  = tid >> 4;        // 0..31
        const int tq = g >> 2;
        const int e0 = (g & 3) * 32;

        const short* qrow = &qkv[(tq * PP + p) * QKV_STRIDE];
        float qv[DD];
#pragma unroll
        for (int dc = 0; dc < 8; ++dc) {
            short8 v = *(const short8*)(qrow + dc * 8);
#pragma unroll
            for (int j = 0; j < 8; ++j) qv[dc * 8 + j] = bf2f(v[j]);
        }
        float sc[TT];
#pragma unroll
        for (int s = 0; s < TT; ++s) {
            const short* krow = &qkv[(s * PP + p) * QKV_STRIDE + DD];
            float a = 0.f;
#pragma unroll
            for (int dc = 0; dc < 8; ++dc) {
                short8 v = *(const short8*)(krow + dc * 8);
#pragma unroll
                for (int j = 0; j < 8; ++j) a += qv[dc * 8 + j] * bf2f(v[j]);
            }
            sc[s] = a * 0.125f;   // 1/sqrt(64)
        }
        float m = sc[0];
#pragma unroll
        for (int s = 1; s < TT; ++s) m = fmaxf(m, sc[s]);
        float sum = 0.f;
#pragma unroll
        for (int s = 0; s < TT; ++s) { sc[s] = __expf(sc[s] - m); sum += sc[s]; }
        const float inv = 1.f / sum;
#pragma unroll
        for (int s = 0; s < TT; ++s) sc[s] *= inv;

        float o[32];
#pragma unroll
        for (int j = 0; j < 32; ++j) o[j] = 0.f;
#pragma unroll
        for (int s = 0; s < TT; ++s) {
            const short* vrow = &qkv[(s * PP + p) * QKV_STRIDE + 2 * DD + e0];
            const float a = sc[s];
#pragma unroll
            for (int ec = 0; ec < 4; ++ec) {
                short8 v = *(const short8*)(vrow + ec * 8);
#pragma unroll
                for (int j = 0; j < 8; ++j) o[ec * 8 + j] += a * bf2f(v[j]);
            }
        }
        // out[b][tq][e][h][w]; lanes 0..15 = consecutive pixels -> 64B segments
        float* op = out + ((size_t)((b * TT + tq) * CC + e0)) * HWp + p0 + p;
#pragma unroll
        for (int e = 0; e < 32; ++e) op[(size_t)e * HWp] = o[e];
    }
}

extern "C" void kernel_launch(void* const* d_in, const int* in_sizes, int n_in,
                              void* d_out, int out_size, void* d_ws, size_t ws_size,
                              hipStream_t stream) {
    const float* x  = (const float*)d_in[0];
    const float* Wq = (const float*)d_in[1];
    const float* bq = (const float*)d_in[2];
    const float* Wk = (const float*)d_in[3];
    const float* bk = (const float*)d_in[4];
    const float* Wv = (const float*)d_in[5];
    const float* bv = (const float*)d_in[6];
    float* out = (float*)d_out;

    const int blocks = 4 * (HWp / PP);   // B=4 x 576 pixel-tiles = 2304
    ta_kernel<<<blocks, 512, 0, stream>>>(x, Wq, bq, Wk, bk, Wv, bv, out);
}